// Round 1
// 576.502 us; speedup vs baseline: 1.0026x; 1.0026x over previous
//
#include <hip/hip_runtime.h>

#define DEVFN __device__ __forceinline__

constexpr int N    = 100000;
constexpr int F_IN = 166;
constexpr int HID  = 128;
constexpr int E    = 1600000;

// ---- workspace layout (bytes, all 16B-aligned) ----
constexpr size_t HW_OFF   = 0;            // hW [N,128] f32      51.2 MB
constexpr size_t ASRC_OFF = 51200000;     // a_src [N,4] f32      1.6 MB
constexpr size_t ADST_OFF = 52800000;     // a_dst [N,4] f32      1.6 MB
constexpr size_t DEG_OFF  = 54400000;     // deg [N] i32        400 KB (zeroed)
constexpr size_t ROW_OFF  = 54800000;     // rowstart [N+1] i32 (ends 55,200,004)
constexpr size_t W1P_OFF  = 55200016;     // W1 packed-transposed [32][64] f32x4 = 32 KB (gap)
constexpr size_t CUR_OFF  = 55300000;     // cursor [N] i32
constexpr size_t BSUM_OFF = 55700000;     // block sums [128] i32
constexpr size_t CSR_OFF  = 55710000;     // csr_src [E] i32     25.6 MB (no self-loops)

constexpr int SCAN_ELEMS = 1024;
constexpr int SCAN_NB    = (N + SCAN_ELEMS - 1) / SCAN_ELEMS;  // 98

constexpr int PROJ_ROWS  = 64;
constexpr int PROJ_NB    = (N + PROJ_ROWS - 1) / PROJ_ROWS;    // 1563

DEVFN float lrelu(float e) { return e > 0.0f ? e : 0.2f * e; }

// ---------------------------------------------------------------------------
// K1 (R7/R10 base + R12 depth-2 W prefetch). Tile 64 rows x 128 cols, 256
// threads, 8 rows x 4 cols per thread. W from global (R5 lesson: LDS-staging
// W regressed). R8/R9 lesson: 4x8 retile regressed (5.3x conflicts) — do not
// revisit. R12: two 4-row W chunks in flight (load->use >= 512 cyc of FMA)
// to cover L2 latency of the streamed Win/Wgat panels.
// Tail: fused dst-degree histogram over EDGES only (self-loops in k_agg).
// ---------------------------------------------------------------------------
__global__ __launch_bounds__(256) void k_proj(
    const float* __restrict__ x, const float* __restrict__ Win,
    const float* __restrict__ bin, const float* __restrict__ Wgat,
    const float* __restrict__ attS, const float* __restrict__ attD,
    float* __restrict__ hW, float* __restrict__ aS, float* __restrict__ aD,
    const int* __restrict__ ei, int* __restrict__ deg)
{
    __shared__ __align__(16) float xs[PROJ_ROWS * 168];   // 43 KB; hs reuses (stride 132)
    float* hs = xs;

    const int t = threadIdx.x;
    const int row0 = blockIdx.x * PROJ_ROWS;
    const int cgrp = t & 31, rgrp = t >> 5;
    const int c0 = cgrp * 4;          // 4 cols
    const int r0 = rgrp * 8;          // 8 rows

    for (int idx = t; idx < PROJ_ROWS * 83; idx += 256) {
        const int r = idx / 83, kk = idx - r * 83;
        float2 v = make_float2(0.f, 0.f);
        if (row0 + r < N)
            v = *(const float2*)&x[(size_t)(row0 + r) * F_IN + 2 * kk];
        *(float2*)&xs[r * 168 + 2 * kk] = v;
    }
    __syncthreads();

    float acc[8][4];
#pragma unroll
    for (int r = 0; r < 8; ++r)
#pragma unroll
        for (int c = 0; c < 4; ++c) acc[r][c] = 0.0f;

#define FMA_BLOCK(SRC, STRIDE, KOFF, W0, W1, W2, W3)                           \
    _Pragma("unroll")                                                          \
    for (int r = 0; r < 8; ++r) {                                              \
        const float4 xv = *(const float4*)&SRC[(r0 + r) * STRIDE + (KOFF)];    \
        acc[r][0] = fmaf(xv.x, W0.x, fmaf(xv.y, W1.x,                          \
                    fmaf(xv.z, W2.x, fmaf(xv.w, W3.x, acc[r][0]))));           \
        acc[r][1] = fmaf(xv.x, W0.y, fmaf(xv.y, W1.y,                          \
                    fmaf(xv.z, W2.y, fmaf(xv.w, W3.y, acc[r][1]))));           \
        acc[r][2] = fmaf(xv.x, W0.z, fmaf(xv.y, W1.z,                          \
                    fmaf(xv.z, W2.z, fmaf(xv.w, W3.z, acc[r][2]))));           \
        acc[r][3] = fmaf(xv.x, W0.w, fmaf(xv.y, W1.w,                          \
                    fmaf(xv.z, W2.w, fmaf(xv.w, W3.w, acc[r][3]))));           \
    }

#define LDW4(DST0, DST1, DST2, DST3, WPTR, KROW)                               \
    DST0 = *(const float4*)&WPTR[(size_t)(KROW + 0) * HID + c0];               \
    DST1 = *(const float4*)&WPTR[(size_t)(KROW + 1) * HID + c0];               \
    DST2 = *(const float4*)&WPTR[(size_t)(KROW + 2) * HID + c0];               \
    DST3 = *(const float4*)&WPTR[(size_t)(KROW + 3) * HID + c0];

    {   // GEMM1: h = relu(x@Win + bin); two chunks (8 k) in flight
        float4 wa0, wa1, wa2, wa3, wb0, wb1, wb2, wb3;
        LDW4(wa0, wa1, wa2, wa3, Win, 0)
        LDW4(wb0, wb1, wb2, wb3, Win, 4)
        for (int k = 0; k < 152; k += 8) {            // chunks 0..148 FMA'd
            float4 p0, p1, p2, p3, q0, q1, q2, q3;
            LDW4(p0, p1, p2, p3, Win, k + 8)
            FMA_BLOCK(xs, 168, k, wa0, wa1, wa2, wa3)
            LDW4(q0, q1, q2, q3, Win, k + 12)
            FMA_BLOCK(xs, 168, k + 4, wb0, wb1, wb2, wb3)
            wa0 = p0; wa1 = p1; wa2 = p2; wa3 = p3;
            wb0 = q0; wb1 = q1; wb2 = q2; wb3 = q3;
        }
        float4 wc0, wc1, wc2, wc3;
        LDW4(wc0, wc1, wc2, wc3, Win, 160)
        FMA_BLOCK(xs, 168, 152, wa0, wa1, wa2, wa3)
        FMA_BLOCK(xs, 168, 156, wb0, wb1, wb2, wb3)
        FMA_BLOCK(xs, 168, 160, wc0, wc1, wc2, wc3)
        const float4 t0 = *(const float4*)&Win[(size_t)164 * HID + c0];
        const float4 t1 = *(const float4*)&Win[(size_t)165 * HID + c0];
#pragma unroll
        for (int r = 0; r < 8; ++r) {
            const float2 xv = *(const float2*)&xs[(r0 + r) * 168 + 164];
            acc[r][0] = fmaf(xv.x, t0.x, fmaf(xv.y, t1.x, acc[r][0]));
            acc[r][1] = fmaf(xv.x, t0.y, fmaf(xv.y, t1.y, acc[r][1]));
            acc[r][2] = fmaf(xv.x, t0.z, fmaf(xv.y, t1.z, acc[r][2]));
            acc[r][3] = fmaf(xv.x, t0.w, fmaf(xv.y, t1.w, acc[r][3]));
        }
    }

    const float4 bb = *(const float4*)&bin[c0];
    __syncthreads();

#pragma unroll
    for (int r = 0; r < 8; ++r) {
        float4 h;
        h.x = fmaxf(acc[r][0] + bb.x, 0.0f);
        h.y = fmaxf(acc[r][1] + bb.y, 0.0f);
        h.z = fmaxf(acc[r][2] + bb.z, 0.0f);
        h.w = fmaxf(acc[r][3] + bb.w, 0.0f);
        *(float4*)&hs[(r0 + r) * 132 + c0] = h;
    }
    __syncthreads();

#pragma unroll
    for (int r = 0; r < 8; ++r)
#pragma unroll
        for (int c = 0; c < 4; ++c) acc[r][c] = 0.0f;

    {   // GEMM2: hW = h@Wgat (K = 128); two chunks (8 k) in flight
        float4 wa0, wa1, wa2, wa3, wb0, wb1, wb2, wb3;
        LDW4(wa0, wa1, wa2, wa3, Wgat, 0)
        LDW4(wb0, wb1, wb2, wb3, Wgat, 4)
        for (int k = 0; k < 112; k += 8) {            // chunks 0..108 FMA'd
            float4 p0, p1, p2, p3, q0, q1, q2, q3;
            LDW4(p0, p1, p2, p3, Wgat, k + 8)
            FMA_BLOCK(hs, 132, k, wa0, wa1, wa2, wa3)
            LDW4(q0, q1, q2, q3, Wgat, k + 12)
            FMA_BLOCK(hs, 132, k + 4, wb0, wb1, wb2, wb3)
            wa0 = p0; wa1 = p1; wa2 = p2; wa3 = p3;
            wb0 = q0; wb1 = q1; wb2 = q2; wb3 = q3;
        }
        float4 wc0, wc1, wc2, wc3, wd0, wd1, wd2, wd3;
        LDW4(wc0, wc1, wc2, wc3, Wgat, 120)
        LDW4(wd0, wd1, wd2, wd3, Wgat, 124)
        FMA_BLOCK(hs, 132, 112, wa0, wa1, wa2, wa3)
        FMA_BLOCK(hs, 132, 116, wb0, wb1, wb2, wb3)
        FMA_BLOCK(hs, 132, 120, wc0, wc1, wc2, wc3)
        FMA_BLOCK(hs, 132, 124, wd0, wd1, wd2, wd3)
    }
#undef FMA_BLOCK
#undef LDW4

    const float4 atS = *(const float4*)&attS[c0];
    const float4 atD = *(const float4*)&attD[c0];
    const int head = cgrp >> 3;

#pragma unroll
    for (int r = 0; r < 8; ++r) {
        const int row = row0 + r0 + r;
        float4 v;
        v.x = acc[r][0]; v.y = acc[r][1]; v.z = acc[r][2]; v.w = acc[r][3];
        if (row < N)
            *(float4*)&hW[(size_t)row * HID + c0] = v;
        float ps = v.x * atS.x + v.y * atS.y + v.z * atS.z + v.w * atS.w;
        float pd = v.x * atD.x + v.y * atD.y + v.z * atD.z + v.w * atD.w;
#pragma unroll
        for (int off = 1; off <= 4; off <<= 1) {
            ps += __shfl_xor(ps, off);
            pd += __shfl_xor(pd, off);
        }
        if ((cgrp & 7) == 0 && row < N) {
            aS[row * 4 + head] = ps;
            aD[row * 4 + head] = pd;
        }
    }

    // ---- fused dst-degree histogram over edges (self-loops excluded) ----
    const int stride = gridDim.x * 256;
    for (int i = blockIdx.x * 256 + t; i < E; i += stride) {
        atomicAdd(&deg[ei[E + i]], 1);
    }
}

// ---------------------------------------------------------------------------
// CSR build: scan1 (block sums) -> scan23 (inline bsum prefix + per-elem scan)
// R12: k_scan1 also packs W1 into W1P[k4*64+o] = float4{W1[4k4+j][o]} so the
// fused MLP in k_agg loads lane-contiguous dwordx4 (128 scalar -> 32 vector).
// ---------------------------------------------------------------------------
__global__ __launch_bounds__(256) void k_scan1(const int* __restrict__ deg,
                                               int* __restrict__ bsum,
                                               const float* __restrict__ W1,
                                               float* __restrict__ W1P)
{
    __shared__ int sd[256];
    const int t = threadIdx.x, b = blockIdx.x;

    // fused W1 pack-transpose (8192 elements, one-time, tiny)
    const int gid = b * 256 + t;
    if (gid < 64 * HID) {
        const int j  = gid & 3;
        const int o  = (gid >> 2) & 63;
        const int k4 = gid >> 8;
        W1P[gid] = W1[(k4 * 4 + j) * 64 + o];
    }

    int s = 0;
    int i0 = b * SCAN_ELEMS + t * 4;
#pragma unroll
    for (int k = 0; k < 4; ++k) {
        int i = i0 + k;
        s += (i < N) ? deg[i] : 0;
    }
    sd[t] = s;
    __syncthreads();
    for (int off = 128; off >= 1; off >>= 1) {
        if (t < off) sd[t] += sd[t + off];
        __syncthreads();
    }
    if (t == 0) bsum[b] = sd[0];
}

__global__ __launch_bounds__(256) void k_scan23(const int* __restrict__ deg,
                                                const int* __restrict__ bsum,
                                                int* __restrict__ rowstart,
                                                int* __restrict__ cursor)
{
    __shared__ int sd[256];
    __shared__ int boff_s;
    const int t = threadIdx.x, b = blockIdx.x;

    sd[t] = (t < b) ? bsum[t] : 0;
    __syncthreads();
    for (int off = 128; off >= 1; off >>= 1) {
        if (t < off) sd[t] += sd[t + off];
        __syncthreads();
    }
    if (t == 0) boff_s = sd[0];
    __syncthreads();
    const int base0 = boff_s;
    __syncthreads();

    const int i0 = b * SCAN_ELEMS + t * 4;
    int d0 = (i0 + 0 < N) ? deg[i0 + 0] : 0;
    int d1 = (i0 + 1 < N) ? deg[i0 + 1] : 0;
    int d2 = (i0 + 2 < N) ? deg[i0 + 2] : 0;
    int d3 = (i0 + 3 < N) ? deg[i0 + 3] : 0;
    int tsum = d0 + d1 + d2 + d3;
    sd[t] = tsum;
    __syncthreads();
    for (int off = 1; off < 256; off <<= 1) {
        int v = (t >= off) ? sd[t - off] : 0;
        __syncthreads();
        sd[t] += v;
        __syncthreads();
    }
    int base = base0 + sd[t] - tsum;
    int e0 = base, e1 = base + d0, e2 = e1 + d1, e3 = e2 + d2;
    if (i0 + 0 < N) { rowstart[i0 + 0] = e0; cursor[i0 + 0] = e0; }
    if (i0 + 1 < N) { rowstart[i0 + 1] = e1; cursor[i0 + 1] = e1; }
    if (i0 + 2 < N) { rowstart[i0 + 2] = e2; cursor[i0 + 2] = e2; }
    if (i0 + 3 < N) { rowstart[i0 + 3] = e3; cursor[i0 + 3] = e3; }
    if (b == 0 && t == 0) rowstart[N] = E;
}

__global__ __launch_bounds__(256) void k_scatter(const int* __restrict__ ei,
                                                 int* __restrict__ cursor,
                                                 int* __restrict__ csr)
{
    int i = (blockIdx.x * 256 + threadIdx.x) * 2;
    if (i >= E) return;
    const int2 s = *(const int2*)&ei[i];
    const int2 d = *(const int2*)&ei[E + i];
    int p0 = atomicAdd(&cursor[d.x], 1);
    csr[p0] = s.x;
    int p1 = atomicAdd(&cursor[d.y], 1);
    csr[p1] = s.y;
}

// ---------------------------------------------------------------------------
// K_agg (R11 + R12): one wave per dst node; lane = slot(8) x cg(8);
// aggregation + FUSED MLP head. Self-loop handled inline by slot-0 lanes.
// R12: MLP reads W1 via packed-transposed W1P (lane-contiguous float4) —
// 32 coalesced dwordx4 instead of 128 scalar dwords per wave, cutting the
// texture-pipe issue pressure that dominated this kernel's VMEM mix (~87%
// of per-wave VMEM instructions were W1 scalar loads).
// ---------------------------------------------------------------------------
__global__ __launch_bounds__(256) void k_agg(
    const int* __restrict__ rowstart, const int* __restrict__ csr,
    const float* __restrict__ aS, const float* __restrict__ aD,
    const float4* __restrict__ hW4, const float4* __restrict__ bgat4,
    const float4* __restrict__ W1P4, const float* __restrict__ b1,
    const float* __restrict__ W2, const float* __restrict__ b2,
    float2* __restrict__ out)
{
    __shared__ __align__(16) float rowbuf[4][HID];   // per-wave 512 B

    const int t = threadIdx.x;
    const int w = t >> 6;
    const int n = blockIdx.x * 4 + w;
    const int lane = t & 63;
    const int slot = lane >> 3;      // 8 parallel edge slots
    const int cg   = lane & 7;       // colgroup: cols [cg*16, cg*16+16)
    const int head = cg >> 1;

    const int r0 = rowstart[n], r1 = rowstart[n + 1];
    const float adh = aD[n * 4 + head];

    float4 a0 = {0.f,0.f,0.f,0.f}, a1 = {0.f,0.f,0.f,0.f};
    float4 a2 = {0.f,0.f,0.f,0.f}, a3 = {0.f,0.f,0.f,0.f};
    float ss = 0.0f;

#define ACC16(H0, H1, H2, H3, X)                                               \
    a0.x = fmaf(H0.x, X, a0.x); a0.y = fmaf(H0.y, X, a0.y);                    \
    a0.z = fmaf(H0.z, X, a0.z); a0.w = fmaf(H0.w, X, a0.w);                    \
    a1.x = fmaf(H1.x, X, a1.x); a1.y = fmaf(H1.y, X, a1.y);                    \
    a1.z = fmaf(H1.z, X, a1.z); a1.w = fmaf(H1.w, X, a1.w);                    \
    a2.x = fmaf(H2.x, X, a2.x); a2.y = fmaf(H2.y, X, a2.y);                    \
    a2.z = fmaf(H2.z, X, a2.z); a2.w = fmaf(H2.w, X, a2.w);                    \
    a3.x = fmaf(H3.x, X, a3.x); a3.y = fmaf(H3.y, X, a3.y);                    \
    a3.z = fmaf(H3.z, X, a3.z); a3.w = fmaf(H3.w, X, a3.w);

    // self-loop: processed once (by slot-0 lanes), reduced with the rest
    if (slot == 0) {
        const float x0 = __expf(lrelu(aS[n * 4 + head] + adh));
        const float4* p0 = &hW4[(size_t)n * 32 + cg * 4];
        const float4 h00 = p0[0], h01 = p0[1], h02 = p0[2], h03 = p0[3];
        ACC16(h00, h01, h02, h03, x0)
        ss += x0;
    }

    int j = r0 + slot;
    for (; j + 8 < r1; j += 16) {
        const int s0 = csr[j], s1 = csr[j + 8];
        const float x0 = __expf(lrelu(aS[s0 * 4 + head] + adh));
        const float x1 = __expf(lrelu(aS[s1 * 4 + head] + adh));
        const float4* p0 = &hW4[(size_t)s0 * 32 + cg * 4];
        const float4* p1 = &hW4[(size_t)s1 * 32 + cg * 4];
        const float4 h00 = p0[0], h01 = p0[1], h02 = p0[2], h03 = p0[3];
        const float4 h10 = p1[0], h11 = p1[1], h12 = p1[2], h13 = p1[3];
        ACC16(h00, h01, h02, h03, x0)
        ACC16(h10, h11, h12, h13, x1)
        ss += x0 + x1;
    }
    if (j < r1) {
        const int s0 = csr[j];
        const float x0 = __expf(lrelu(aS[s0 * 4 + head] + adh));
        const float4* p0 = &hW4[(size_t)s0 * 32 + cg * 4];
        const float4 h00 = p0[0], h01 = p0[1], h02 = p0[2], h03 = p0[3];
        ACC16(h00, h01, h02, h03, x0)
        ss += x0;
    }
#undef ACC16

    // reduce across the 8 edge-slots (lane bits 3..5)
#pragma unroll
    for (int off = 8; off <= 32; off <<= 1) {
        a0.x += __shfl_xor(a0.x, off); a0.y += __shfl_xor(a0.y, off);
        a0.z += __shfl_xor(a0.z, off); a0.w += __shfl_xor(a0.w, off);
        a1.x += __shfl_xor(a1.x, off); a1.y += __shfl_xor(a1.y, off);
        a1.z += __shfl_xor(a1.z, off); a1.w += __shfl_xor(a1.w, off);
        a2.x += __shfl_xor(a2.x, off); a2.y += __shfl_xor(a2.y, off);
        a2.z += __shfl_xor(a2.z, off); a2.w += __shfl_xor(a2.w, off);
        a3.x += __shfl_xor(a3.x, off); a3.y += __shfl_xor(a3.y, off);
        a3.z += __shfl_xor(a3.z, off); a3.w += __shfl_xor(a3.w, off);
        ss += __shfl_xor(ss, off);
    }

    // slot-0 lanes own 16 cols each: normalize, +b_gat, park in LDS rowbuf
    if (slot == 0) {
        const float inv = 1.0f / (ss + 1e-16f);
        const float4 bg0 = bgat4[cg * 4 + 0];
        const float4 bg1 = bgat4[cg * 4 + 1];
        const float4 bg2 = bgat4[cg * 4 + 2];
        const float4 bg3 = bgat4[cg * 4 + 3];
        float4 o0, o1, o2, o3;
        o0.x = a0.x * inv + bg0.x; o0.y = a0.y * inv + bg0.y;
        o0.z = a0.z * inv + bg0.z; o0.w = a0.w * inv + bg0.w;
        o1.x = a1.x * inv + bg1.x; o1.y = a1.y * inv + bg1.y;
        o1.z = a1.z * inv + bg1.z; o1.w = a1.w * inv + bg1.w;
        o2.x = a2.x * inv + bg2.x; o2.y = a2.y * inv + bg2.y;
        o2.z = a2.z * inv + bg2.z; o2.w = a2.w * inv + bg2.w;
        o3.x = a3.x * inv + bg3.x; o3.y = a3.y * inv + bg3.y;
        o3.z = a3.z * inv + bg3.z; o3.w = a3.w * inv + bg3.w;
        float* pr = &rowbuf[w][cg * 16];
        *(float4*)&pr[0]  = o0;
        *(float4*)&pr[4]  = o1;
        *(float4*)&pr[8]  = o2;
        *(float4*)&pr[12] = o3;
    }
    // same-wave LDS write->read: in-order per wave, no barrier needed

    // ---- fused MLP head: h2[lane] = relu(row@W1+b1); logits = h2@W2+b2 ----
    float acc = b1[lane];
    const float4* wp = &W1P4[lane];
#pragma unroll 4
    for (int k4 = 0; k4 < 32; ++k4) {
        const float4 rv = *(const float4*)&rowbuf[w][k4 * 4];
        const float4 wv = wp[k4 * 64];
        acc = fmaf(rv.x, wv.x, fmaf(rv.y, wv.y,
              fmaf(rv.z, wv.z, fmaf(rv.w, wv.w, acc))));
    }
    acc = fmaxf(acc, 0.0f);

    const float2 w2v = *(const float2*)&W2[lane * 2];
    float l0 = acc * w2v.x;
    float l1 = acc * w2v.y;
#pragma unroll
    for (int off = 32; off >= 1; off >>= 1) {
        l0 += __shfl_xor(l0, off);
        l1 += __shfl_xor(l1, off);
    }
    if (lane == 0) out[n] = make_float2(l0 + b2[0], l1 + b2[1]);
}

extern "C" void kernel_launch(void* const* d_in, const int* in_sizes, int n_in,
                              void* d_out, int out_size, void* d_ws, size_t ws_size,
                              hipStream_t stream) {
    const float* x     = (const float*)d_in[0];
    const int*   ei    = (const int*)d_in[1];
    const float* Win   = (const float*)d_in[2];
    const float* bin   = (const float*)d_in[3];
    const float* Wgat  = (const float*)d_in[4];
    const float* attS  = (const float*)d_in[5];
    const float* attD  = (const float*)d_in[6];
    const float* bgat  = (const float*)d_in[7];
    const float* W1    = (const float*)d_in[8];
    const float* b1    = (const float*)d_in[9];
    const float* W2    = (const float*)d_in[10];
    const float* b2    = (const float*)d_in[11];

    char* ws = (char*)d_ws;
    float* hW    = (float*)(ws + HW_OFF);
    float* aS    = (float*)(ws + ASRC_OFF);
    float* aD    = (float*)(ws + ADST_OFF);
    int*   deg   = (int*)(ws + DEG_OFF);
    int*   row   = (int*)(ws + ROW_OFF);
    float* W1P   = (float*)(ws + W1P_OFF);
    int*   cur   = (int*)(ws + CUR_OFF);
    int*   bsum  = (int*)(ws + BSUM_OFF);
    int*   csr   = (int*)(ws + CSR_OFF);

    hipMemsetAsync(ws + DEG_OFF, 0, N * sizeof(int), stream);

    k_proj<<<PROJ_NB, 256, 0, stream>>>(x, Win, bin, Wgat, attS, attD,
                                        hW, aS, aD, ei, deg);
    k_scan1<<<SCAN_NB, 256, 0, stream>>>(deg, bsum, W1, W1P);
    k_scan23<<<SCAN_NB, 256, 0, stream>>>(deg, bsum, row, cur);
    k_scatter<<<(E / 2 + 255) / 256, 256, 0, stream>>>(ei, cur, csr);
    k_agg<<<N / 4, 256, 0, stream>>>(row, csr, aS, aD, (const float4*)hW,
                                     (const float4*)bgat, (const float4*)W1P,
                                     b1, W2, b2, (float2*)d_out);
}

// Round 2
// 541.145 us; speedup vs baseline: 1.0681x; 1.0653x over previous
//
#include <hip/hip_runtime.h>
#include <hip/hip_fp16.h>

#define DEVFN __device__ __forceinline__

constexpr int N    = 100000;
constexpr int F_IN = 166;
constexpr int HID  = 128;
constexpr int E    = 1600000;

// ---- workspace layout (bytes, all 16B-aligned) ----
constexpr size_t HW_OFF   = 0;            // hW [N,128] fp16     25.6 MB (R13: was f32)
constexpr size_t ASRC_OFF = 51200000;     // a_src [N,4] f32      1.6 MB
constexpr size_t ADST_OFF = 52800000;     // a_dst [N,4] f32      1.6 MB
constexpr size_t DEG_OFF  = 54400000;     // deg [N] i32        400 KB (zeroed)
constexpr size_t ROW_OFF  = 54800000;     // rowstart [N+1] i32 (ends 55,200,004)
constexpr size_t W1P_OFF  = 55200016;     // W1 packed-transposed [32][64] f32x4 = 32 KB
constexpr size_t CUR_OFF  = 55300000;     // cursor [N] i32
constexpr size_t BSUM_OFF = 55700000;     // block sums [128] i32
constexpr size_t CSR_OFF  = 55710000;     // csr_src [E] i32     25.6 MB (no self-loops)

constexpr int SCAN_ELEMS = 1024;
constexpr int SCAN_NB    = (N + SCAN_ELEMS - 1) / SCAN_ELEMS;  // 98

constexpr int PROJ_ROWS  = 64;
constexpr int PROJ_NB    = (N + PROJ_ROWS - 1) / PROJ_ROWS;    // 1563

DEVFN float lrelu(float e) { return e > 0.0f ? e : 0.2f * e; }

// 16 half-precision messages (2x float4 raw) fma'd into 4x float4 f32 accs.
// Compiler emits v_fma_mix_f32 — no explicit cvt cost.
DEVFN void acc16h(const float4& q0, const float4& q1, const float x,
                  float4& a0, float4& a1, float4& a2, float4& a3)
{
    const __half2* h = (const __half2*)&q0;
    a0.x = fmaf(__low2float(h[0]),  x, a0.x);
    a0.y = fmaf(__high2float(h[0]), x, a0.y);
    a0.z = fmaf(__low2float(h[1]),  x, a0.z);
    a0.w = fmaf(__high2float(h[1]), x, a0.w);
    a1.x = fmaf(__low2float(h[2]),  x, a1.x);
    a1.y = fmaf(__high2float(h[2]), x, a1.y);
    a1.z = fmaf(__low2float(h[3]),  x, a1.z);
    a1.w = fmaf(__high2float(h[3]), x, a1.w);
    const __half2* g = (const __half2*)&q1;
    a2.x = fmaf(__low2float(g[0]),  x, a2.x);
    a2.y = fmaf(__high2float(g[0]), x, a2.y);
    a2.z = fmaf(__low2float(g[1]),  x, a2.z);
    a2.w = fmaf(__high2float(g[1]), x, a2.w);
    a3.x = fmaf(__low2float(g[2]),  x, a3.x);
    a3.y = fmaf(__high2float(g[2]), x, a3.y);
    a3.z = fmaf(__low2float(g[3]),  x, a3.z);
    a3.w = fmaf(__high2float(g[3]), x, a3.w);
}

// ---------------------------------------------------------------------------
// K1 (R7/R10 base + R12 depth-2 W prefetch + R13 fp16 hW store). Tile 64 rows
// x 128 cols, 256 threads, 8 rows x 4 cols per thread. W from global (R5
// lesson: LDS-staging W regressed). R8/R9 lesson: 4x8 retile regressed — do
// not revisit. aS/aD still computed from f32 accs (full precision); only the
// STORED hW is fp16 (halves k_agg's random-gather bytes, its BW wall).
// ---------------------------------------------------------------------------
__global__ __launch_bounds__(256) void k_proj(
    const float* __restrict__ x, const float* __restrict__ Win,
    const float* __restrict__ bin, const float* __restrict__ Wgat,
    const float* __restrict__ attS, const float* __restrict__ attD,
    __half* __restrict__ hWh, float* __restrict__ aS, float* __restrict__ aD,
    const int* __restrict__ ei, int* __restrict__ deg)
{
    __shared__ __align__(16) float xs[PROJ_ROWS * 168];   // 43 KB; hs reuses (stride 132)
    float* hs = xs;

    const int t = threadIdx.x;
    const int row0 = blockIdx.x * PROJ_ROWS;
    const int cgrp = t & 31, rgrp = t >> 5;
    const int c0 = cgrp * 4;          // 4 cols
    const int r0 = rgrp * 8;          // 8 rows

    for (int idx = t; idx < PROJ_ROWS * 83; idx += 256) {
        const int r = idx / 83, kk = idx - r * 83;
        float2 v = make_float2(0.f, 0.f);
        if (row0 + r < N)
            v = *(const float2*)&x[(size_t)(row0 + r) * F_IN + 2 * kk];
        *(float2*)&xs[r * 168 + 2 * kk] = v;
    }
    __syncthreads();

    float acc[8][4];
#pragma unroll
    for (int r = 0; r < 8; ++r)
#pragma unroll
        for (int c = 0; c < 4; ++c) acc[r][c] = 0.0f;

#define FMA_BLOCK(SRC, STRIDE, KOFF, W0, W1, W2, W3)                           \
    _Pragma("unroll")                                                          \
    for (int r = 0; r < 8; ++r) {                                              \
        const float4 xv = *(const float4*)&SRC[(r0 + r) * STRIDE + (KOFF)];    \
        acc[r][0] = fmaf(xv.x, W0.x, fmaf(xv.y, W1.x,                          \
                    fmaf(xv.z, W2.x, fmaf(xv.w, W3.x, acc[r][0]))));           \
        acc[r][1] = fmaf(xv.x, W0.y, fmaf(xv.y, W1.y,                          \
                    fmaf(xv.z, W2.y, fmaf(xv.w, W3.y, acc[r][1]))));           \
        acc[r][2] = fmaf(xv.x, W0.z, fmaf(xv.y, W1.z,                          \
                    fmaf(xv.z, W2.z, fmaf(xv.w, W3.z, acc[r][2]))));           \
        acc[r][3] = fmaf(xv.x, W0.w, fmaf(xv.y, W1.w,                          \
                    fmaf(xv.z, W2.w, fmaf(xv.w, W3.w, acc[r][3]))));           \
    }

#define LDW4(DST0, DST1, DST2, DST3, WPTR, KROW)                               \
    DST0 = *(const float4*)&WPTR[(size_t)(KROW + 0) * HID + c0];               \
    DST1 = *(const float4*)&WPTR[(size_t)(KROW + 1) * HID + c0];               \
    DST2 = *(const float4*)&WPTR[(size_t)(KROW + 2) * HID + c0];               \
    DST3 = *(const float4*)&WPTR[(size_t)(KROW + 3) * HID + c0];

    {   // GEMM1: h = relu(x@Win + bin); two chunks (8 k) in flight
        float4 wa0, wa1, wa2, wa3, wb0, wb1, wb2, wb3;
        LDW4(wa0, wa1, wa2, wa3, Win, 0)
        LDW4(wb0, wb1, wb2, wb3, Win, 4)
        for (int k = 0; k < 152; k += 8) {            // chunks 0..148 FMA'd
            float4 p0, p1, p2, p3, q0, q1, q2, q3;
            LDW4(p0, p1, p2, p3, Win, k + 8)
            FMA_BLOCK(xs, 168, k, wa0, wa1, wa2, wa3)
            LDW4(q0, q1, q2, q3, Win, k + 12)
            FMA_BLOCK(xs, 168, k + 4, wb0, wb1, wb2, wb3)
            wa0 = p0; wa1 = p1; wa2 = p2; wa3 = p3;
            wb0 = q0; wb1 = q1; wb2 = q2; wb3 = q3;
        }
        float4 wc0, wc1, wc2, wc3;
        LDW4(wc0, wc1, wc2, wc3, Win, 160)
        FMA_BLOCK(xs, 168, 152, wa0, wa1, wa2, wa3)
        FMA_BLOCK(xs, 168, 156, wb0, wb1, wb2, wb3)
        FMA_BLOCK(xs, 168, 160, wc0, wc1, wc2, wc3)
        const float4 t0 = *(const float4*)&Win[(size_t)164 * HID + c0];
        const float4 t1 = *(const float4*)&Win[(size_t)165 * HID + c0];
#pragma unroll
        for (int r = 0; r < 8; ++r) {
            const float2 xv = *(const float2*)&xs[(r0 + r) * 168 + 164];
            acc[r][0] = fmaf(xv.x, t0.x, fmaf(xv.y, t1.x, acc[r][0]));
            acc[r][1] = fmaf(xv.x, t0.y, fmaf(xv.y, t1.y, acc[r][1]));
            acc[r][2] = fmaf(xv.x, t0.z, fmaf(xv.y, t1.z, acc[r][2]));
            acc[r][3] = fmaf(xv.x, t0.w, fmaf(xv.y, t1.w, acc[r][3]));
        }
    }

    const float4 bb = *(const float4*)&bin[c0];
    __syncthreads();

#pragma unroll
    for (int r = 0; r < 8; ++r) {
        float4 h;
        h.x = fmaxf(acc[r][0] + bb.x, 0.0f);
        h.y = fmaxf(acc[r][1] + bb.y, 0.0f);
        h.z = fmaxf(acc[r][2] + bb.z, 0.0f);
        h.w = fmaxf(acc[r][3] + bb.w, 0.0f);
        *(float4*)&hs[(r0 + r) * 132 + c0] = h;
    }
    __syncthreads();

#pragma unroll
    for (int r = 0; r < 8; ++r)
#pragma unroll
        for (int c = 0; c < 4; ++c) acc[r][c] = 0.0f;

    {   // GEMM2: hW = h@Wgat (K = 128); two chunks (8 k) in flight
        float4 wa0, wa1, wa2, wa3, wb0, wb1, wb2, wb3;
        LDW4(wa0, wa1, wa2, wa3, Wgat, 0)
        LDW4(wb0, wb1, wb2, wb3, Wgat, 4)
        for (int k = 0; k < 112; k += 8) {            // chunks 0..108 FMA'd
            float4 p0, p1, p2, p3, q0, q1, q2, q3;
            LDW4(p0, p1, p2, p3, Wgat, k + 8)
            FMA_BLOCK(hs, 132, k, wa0, wa1, wa2, wa3)
            LDW4(q0, q1, q2, q3, Wgat, k + 12)
            FMA_BLOCK(hs, 132, k + 4, wb0, wb1, wb2, wb3)
            wa0 = p0; wa1 = p1; wa2 = p2; wa3 = p3;
            wb0 = q0; wb1 = q1; wb2 = q2; wb3 = q3;
        }
        float4 wc0, wc1, wc2, wc3, wd0, wd1, wd2, wd3;
        LDW4(wc0, wc1, wc2, wc3, Wgat, 120)
        LDW4(wd0, wd1, wd2, wd3, Wgat, 124)
        FMA_BLOCK(hs, 132, 112, wa0, wa1, wa2, wa3)
        FMA_BLOCK(hs, 132, 116, wb0, wb1, wb2, wb3)
        FMA_BLOCK(hs, 132, 120, wc0, wc1, wc2, wc3)
        FMA_BLOCK(hs, 132, 124, wd0, wd1, wd2, wd3)
    }
#undef FMA_BLOCK
#undef LDW4

    const float4 atS = *(const float4*)&attS[c0];
    const float4 atD = *(const float4*)&attD[c0];
    const int head = cgrp >> 3;

#pragma unroll
    for (int r = 0; r < 8; ++r) {
        const int row = row0 + r0 + r;
        float4 v;
        v.x = acc[r][0]; v.y = acc[r][1]; v.z = acc[r][2]; v.w = acc[r][3];
        if (row < N) {
            // R13: fp16 store (8 B per thread-row), aS/aD stay f32-derived
            const __half2 p01 = __float22half2_rn(make_float2(v.x, v.y));
            const __half2 p23 = __float22half2_rn(make_float2(v.z, v.w));
            uint2 pk;
            pk.x = *(const unsigned int*)&p01;
            pk.y = *(const unsigned int*)&p23;
            *(uint2*)&hWh[(size_t)row * HID + c0] = pk;
        }
        float ps = v.x * atS.x + v.y * atS.y + v.z * atS.z + v.w * atS.w;
        float pd = v.x * atD.x + v.y * atD.y + v.z * atD.z + v.w * atD.w;
#pragma unroll
        for (int off = 1; off <= 4; off <<= 1) {
            ps += __shfl_xor(ps, off);
            pd += __shfl_xor(pd, off);
        }
        if ((cgrp & 7) == 0 && row < N) {
            aS[row * 4 + head] = ps;
            aD[row * 4 + head] = pd;
        }
    }

    // ---- fused dst-degree histogram over edges (self-loops excluded) ----
    const int stride = gridDim.x * 256;
    for (int i = blockIdx.x * 256 + t; i < E; i += stride) {
        atomicAdd(&deg[ei[E + i]], 1);
    }
}

// ---------------------------------------------------------------------------
// CSR build: scan1 (block sums + fused W1 pack) -> scan23 -> scatter
// ---------------------------------------------------------------------------
__global__ __launch_bounds__(256) void k_scan1(const int* __restrict__ deg,
                                               int* __restrict__ bsum,
                                               const float* __restrict__ W1,
                                               float* __restrict__ W1P)
{
    __shared__ int sd[256];
    const int t = threadIdx.x, b = blockIdx.x;

    // fused W1 pack-transpose (8192 elements, one-time, tiny)
    const int gid = b * 256 + t;
    if (gid < 64 * HID) {
        const int j  = gid & 3;
        const int o  = (gid >> 2) & 63;
        const int k4 = gid >> 8;
        W1P[gid] = W1[(k4 * 4 + j) * 64 + o];
    }

    int s = 0;
    int i0 = b * SCAN_ELEMS + t * 4;
#pragma unroll
    for (int k = 0; k < 4; ++k) {
        int i = i0 + k;
        s += (i < N) ? deg[i] : 0;
    }
    sd[t] = s;
    __syncthreads();
    for (int off = 128; off >= 1; off >>= 1) {
        if (t < off) sd[t] += sd[t + off];
        __syncthreads();
    }
    if (t == 0) bsum[b] = sd[0];
}

__global__ __launch_bounds__(256) void k_scan23(const int* __restrict__ deg,
                                                const int* __restrict__ bsum,
                                                int* __restrict__ rowstart,
                                                int* __restrict__ cursor)
{
    __shared__ int sd[256];
    __shared__ int boff_s;
    const int t = threadIdx.x, b = blockIdx.x;

    sd[t] = (t < b) ? bsum[t] : 0;
    __syncthreads();
    for (int off = 128; off >= 1; off >>= 1) {
        if (t < off) sd[t] += sd[t + off];
        __syncthreads();
    }
    if (t == 0) boff_s = sd[0];
    __syncthreads();
    const int base0 = boff_s;
    __syncthreads();

    const int i0 = b * SCAN_ELEMS + t * 4;
    int d0 = (i0 + 0 < N) ? deg[i0 + 0] : 0;
    int d1 = (i0 + 1 < N) ? deg[i0 + 1] : 0;
    int d2 = (i0 + 2 < N) ? deg[i0 + 2] : 0;
    int d3 = (i0 + 3 < N) ? deg[i0 + 3] : 0;
    int tsum = d0 + d1 + d2 + d3;
    sd[t] = tsum;
    __syncthreads();
    for (int off = 1; off < 256; off <<= 1) {
        int v = (t >= off) ? sd[t - off] : 0;
        __syncthreads();
        sd[t] += v;
        __syncthreads();
    }
    int base = base0 + sd[t] - tsum;
    int e0 = base, e1 = base + d0, e2 = e1 + d1, e3 = e2 + d2;
    if (i0 + 0 < N) { rowstart[i0 + 0] = e0; cursor[i0 + 0] = e0; }
    if (i0 + 1 < N) { rowstart[i0 + 1] = e1; cursor[i0 + 1] = e1; }
    if (i0 + 2 < N) { rowstart[i0 + 2] = e2; cursor[i0 + 2] = e2; }
    if (i0 + 3 < N) { rowstart[i0 + 3] = e3; cursor[i0 + 3] = e3; }
    if (b == 0 && t == 0) rowstart[N] = E;
}

__global__ __launch_bounds__(256) void k_scatter(const int* __restrict__ ei,
                                                 int* __restrict__ cursor,
                                                 int* __restrict__ csr)
{
    int i = (blockIdx.x * 256 + threadIdx.x) * 2;
    if (i >= E) return;
    const int2 s = *(const int2*)&ei[i];
    const int2 d = *(const int2*)&ei[E + i];
    int p0 = atomicAdd(&cursor[d.x], 1);
    csr[p0] = s.x;
    int p1 = atomicAdd(&cursor[d.y], 1);
    csr[p1] = s.y;
}

// ---------------------------------------------------------------------------
// K_agg (R11 + R12 + R13): one wave per dst node; lane = slot(8) x cg(8);
// aggregation + FUSED MLP head. Self-loop inline (slot-0 lanes).
// R13: hW gathered as fp16 — halves the random-gather bytes that form the
// ~2.2 TB/s BW wall this kernel sits on (Little's-law: 31K-cycle wave
// lifetimes = queueing, not issue). v_fma_mix_f32 accumulates in f32.
// MLP acc split into 2 chains (ILP).
// ---------------------------------------------------------------------------
__global__ __launch_bounds__(256) void k_agg(
    const int* __restrict__ rowstart, const int* __restrict__ csr,
    const float* __restrict__ aS, const float* __restrict__ aD,
    const __half* __restrict__ hWh, const float4* __restrict__ bgat4,
    const float4* __restrict__ W1P4, const float* __restrict__ b1,
    const float* __restrict__ W2, const float* __restrict__ b2,
    float2* __restrict__ out)
{
    __shared__ __align__(16) float rowbuf[4][HID];   // per-wave 512 B

    const int t = threadIdx.x;
    const int w = t >> 6;
    const int n = blockIdx.x * 4 + w;
    const int lane = t & 63;
    const int slot = lane >> 3;      // 8 parallel edge slots
    const int cg   = lane & 7;       // colgroup: cols [cg*16, cg*16+16)
    const int head = cg >> 1;

    const int r0 = rowstart[n], r1 = rowstart[n + 1];
    const float adh = aD[n * 4 + head];

    float4 a0 = {0.f,0.f,0.f,0.f}, a1 = {0.f,0.f,0.f,0.f};
    float4 a2 = {0.f,0.f,0.f,0.f}, a3 = {0.f,0.f,0.f,0.f};
    float ss = 0.0f;

    // self-loop: processed once (by slot-0 lanes), reduced with the rest
    if (slot == 0) {
        const float x0 = __expf(lrelu(aS[n * 4 + head] + adh));
        const float4* p0 = (const float4*)&hWh[(size_t)n * HID + cg * 16];
        const float4 q0 = p0[0], q1 = p0[1];
        acc16h(q0, q1, x0, a0, a1, a2, a3);
        ss += x0;
    }

    int j = r0 + slot;
    for (; j + 8 < r1; j += 16) {
        const int s0 = csr[j], s1 = csr[j + 8];
        const float x0 = __expf(lrelu(aS[s0 * 4 + head] + adh));
        const float x1 = __expf(lrelu(aS[s1 * 4 + head] + adh));
        const float4* p0 = (const float4*)&hWh[(size_t)s0 * HID + cg * 16];
        const float4* p1 = (const float4*)&hWh[(size_t)s1 * HID + cg * 16];
        const float4 q00 = p0[0], q01 = p0[1];
        const float4 q10 = p1[0], q11 = p1[1];
        acc16h(q00, q01, x0, a0, a1, a2, a3);
        acc16h(q10, q11, x1, a0, a1, a2, a3);
        ss += x0 + x1;
    }
    if (j < r1) {
        const int s0 = csr[j];
        const float x0 = __expf(lrelu(aS[s0 * 4 + head] + adh));
        const float4* p0 = (const float4*)&hWh[(size_t)s0 * HID + cg * 16];
        const float4 q0 = p0[0], q1 = p0[1];
        acc16h(q0, q1, x0, a0, a1, a2, a3);
        ss += x0;
    }

    // reduce across the 8 edge-slots (lane bits 3..5)
#pragma unroll
    for (int off = 8; off <= 32; off <<= 1) {
        a0.x += __shfl_xor(a0.x, off); a0.y += __shfl_xor(a0.y, off);
        a0.z += __shfl_xor(a0.z, off); a0.w += __shfl_xor(a0.w, off);
        a1.x += __shfl_xor(a1.x, off); a1.y += __shfl_xor(a1.y, off);
        a1.z += __shfl_xor(a1.z, off); a1.w += __shfl_xor(a1.w, off);
        a2.x += __shfl_xor(a2.x, off); a2.y += __shfl_xor(a2.y, off);
        a2.z += __shfl_xor(a2.z, off); a2.w += __shfl_xor(a2.w, off);
        a3.x += __shfl_xor(a3.x, off); a3.y += __shfl_xor(a3.y, off);
        a3.z += __shfl_xor(a3.z, off); a3.w += __shfl_xor(a3.w, off);
        ss += __shfl_xor(ss, off);
    }

    // slot-0 lanes own 16 cols each: normalize, +b_gat, park in LDS rowbuf
    if (slot == 0) {
        const float inv = 1.0f / (ss + 1e-16f);
        const float4 bg0 = bgat4[cg * 4 + 0];
        const float4 bg1 = bgat4[cg * 4 + 1];
        const float4 bg2 = bgat4[cg * 4 + 2];
        const float4 bg3 = bgat4[cg * 4 + 3];
        float4 o0, o1, o2, o3;
        o0.x = a0.x * inv + bg0.x; o0.y = a0.y * inv + bg0.y;
        o0.z = a0.z * inv + bg0.z; o0.w = a0.w * inv + bg0.w;
        o1.x = a1.x * inv + bg1.x; o1.y = a1.y * inv + bg1.y;
        o1.z = a1.z * inv + bg1.z; o1.w = a1.w * inv + bg1.w;
        o2.x = a2.x * inv + bg2.x; o2.y = a2.y * inv + bg2.y;
        o2.z = a2.z * inv + bg2.z; o2.w = a2.w * inv + bg2.w;
        o3.x = a3.x * inv + bg3.x; o3.y = a3.y * inv + bg3.y;
        o3.z = a3.z * inv + bg3.z; o3.w = a3.w * inv + bg3.w;
        float* pr = &rowbuf[w][cg * 16];
        *(float4*)&pr[0]  = o0;
        *(float4*)&pr[4]  = o1;
        *(float4*)&pr[8]  = o2;
        *(float4*)&pr[12] = o3;
    }
    // same-wave LDS write->read: in-order per wave, no barrier needed

    // ---- fused MLP head: h2[lane] = relu(row@W1+b1); logits = h2@W2+b2 ----
    float accA = b1[lane];
    float accB = 0.0f;
    const float4* wp = &W1P4[lane];
#pragma unroll 4
    for (int k4 = 0; k4 < 32; k4 += 2) {
        const float4 rv0 = *(const float4*)&rowbuf[w][k4 * 4];
        const float4 wv0 = wp[k4 * 64];
        const float4 rv1 = *(const float4*)&rowbuf[w][k4 * 4 + 4];
        const float4 wv1 = wp[(k4 + 1) * 64];
        accA = fmaf(rv0.x, wv0.x, fmaf(rv0.y, wv0.y,
               fmaf(rv0.z, wv0.z, fmaf(rv0.w, wv0.w, accA))));
        accB = fmaf(rv1.x, wv1.x, fmaf(rv1.y, wv1.y,
               fmaf(rv1.z, wv1.z, fmaf(rv1.w, wv1.w, accB))));
    }
    const float acc = fmaxf(accA + accB, 0.0f);

    const float2 w2v = *(const float2*)&W2[lane * 2];
    float l0 = acc * w2v.x;
    float l1 = acc * w2v.y;
#pragma unroll
    for (int off = 32; off >= 1; off >>= 1) {
        l0 += __shfl_xor(l0, off);
        l1 += __shfl_xor(l1, off);
    }
    if (lane == 0) out[n] = make_float2(l0 + b2[0], l1 + b2[1]);
}

extern "C" void kernel_launch(void* const* d_in, const int* in_sizes, int n_in,
                              void* d_out, int out_size, void* d_ws, size_t ws_size,
                              hipStream_t stream) {
    const float* x     = (const float*)d_in[0];
    const int*   ei    = (const int*)d_in[1];
    const float* Win   = (const float*)d_in[2];
    const float* bin   = (const float*)d_in[3];
    const float* Wgat  = (const float*)d_in[4];
    const float* attS  = (const float*)d_in[5];
    const float* attD  = (const float*)d_in[6];
    const float* bgat  = (const float*)d_in[7];
    const float* W1    = (const float*)d_in[8];
    const float* b1    = (const float*)d_in[9];
    const float* W2    = (const float*)d_in[10];
    const float* b2    = (const float*)d_in[11];

    char* ws = (char*)d_ws;
    __half* hWh  = (__half*)(ws + HW_OFF);
    float* aS    = (float*)(ws + ASRC_OFF);
    float* aD    = (float*)(ws + ADST_OFF);
    int*   deg   = (int*)(ws + DEG_OFF);
    int*   row   = (int*)(ws + ROW_OFF);
    float* W1P   = (float*)(ws + W1P_OFF);
    int*   cur   = (int*)(ws + CUR_OFF);
    int*   bsum  = (int*)(ws + BSUM_OFF);
    int*   csr   = (int*)(ws + CSR_OFF);

    hipMemsetAsync(ws + DEG_OFF, 0, N * sizeof(int), stream);

    k_proj<<<PROJ_NB, 256, 0, stream>>>(x, Win, bin, Wgat, attS, attD,
                                        hWh, aS, aD, ei, deg);
    k_scan1<<<SCAN_NB, 256, 0, stream>>>(deg, bsum, W1, W1P);
    k_scan23<<<SCAN_NB, 256, 0, stream>>>(deg, bsum, row, cur);
    k_scatter<<<(E / 2 + 255) / 256, 256, 0, stream>>>(ei, cur, csr);
    k_agg<<<N / 4, 256, 0, stream>>>(row, csr, aS, aD, hWh,
                                     (const float4*)bgat, (const float4*)W1P,
                                     b1, W2, b2, (float2*)d_out);
}